// Round 8
// baseline (117.149 us; speedup 1.0000x reference)
//
#include <hip/hip_runtime.h>
#include <hip/hip_bf16.h>

// flex_conv via MFMA + cross-tile double-buffered async pipeline (v8).
//
// Math (unchanged, validated): t[k=ic*4+d][pixel]: t_d = ctr_d*Xs - PX_d
// (d<3), t_3 = Xs; out[o][pixel] = Kmat[o][k] . t[k][pixel] -> 16x16x32 bf16
// MFMA (A[m=p][k], B[k][n=p], D row=c*4+r col=p).
//
// v1-v7 post-mortem: every schedule lands at 2.3-2.8 TB/s of its own traffic
// (fill kernel: 6.4 TB/s).  Eliminated: barriers, occupancy capacity, LDS
// staging, VALU volume, store coalescing.  Surviving theory: memory-in-flight
// DUTY CYCLE -- each block's 20.7 KB staging burst drains to zero at the
// barrier, then computes with nothing in flight (~40% duty = ~40% of BW).
// The one real pipeline test (v2) was confounded: 512-block grid = 2/CU work,
// no backfill, 8% occupancy.
//
// v8 = proper pipeline: block owns 4 consecutive row-pair tiles, 2-slot LDS
// ring (41.3 KB -> 3 blocks/CU, 12 waves/CU).  Per tile: issue stage(t+1) ->
// compute(t) -> barrier (drains prefetch AFTER compute, so DMA latency hides
// under compute; barrier also protects slot reuse: stage(t+2) overwrites the
// slot read by compute(t), which completed at that barrier).  Grid 1024
// blocks = 4/CU of work -> backfill.  Consecutive tiles share 2/4 halo rows
// -> L2-warm refetch (FETCH down).  Staging/compute bodies = v4 verbatim.

#define HH 64
#define WW 512
#define HP 62
#define WP 510
#define IC 16
#define OC 32
#define BS 16
#define RB 2            // output rows per tile
#define TR (RB + 2)     // staged input rows per tile = 4
#define TC 64           // output cols per block
#define LC 68           // LDS row length in floats (need 66; 68 = 17 float4)
#define NPL 19          // planes staged: 16 x + 3 pts
#define CPR 17          // float4 chunks per row (17*4 = 68)
#define NROWS (NPL * TR)        // 76
#define NCHUNK (NROWS * CPR)    // 1292
#define TILEF (NPL * TR * LC)   // 5168 floats per slot
#define NT 4            // tiles per block

typedef __attribute__((ext_vector_type(8))) short short8;
typedef __attribute__((ext_vector_type(4))) float f32x4;

static __device__ __forceinline__ short f2bf(float f) {
    union { __hip_bfloat16 h; short s; } u;
    u.h = __float2bfloat16(f);
    return u.s;
}

// v4's staging body, parameterized by LDS slot base and tile top row i0.
static __device__ __forceinline__ void stage_tile(
    const float* __restrict__ xb, const float* __restrict__ pb,
    float* slot, int i0, int j0, int tid)
{
    #pragma unroll
    for (int rnd = 0; rnd < 6; ++rnd) {
        const int cid = tid + rnd * 256;
        if (cid < NCHUNK) {
            const int row = cid / CPR;           // 0..75 = plane*TR + rr
            const int chunk = cid - row * CPR;   // 0..16
            const int plane = row / TR;          // 0..18
            const int rr = row - plane * TR;     // 0..3
            const float* base = (plane < IC)
                ? (xb + (size_t)plane * HH * WW)
                : (pb + (size_t)(plane - IC) * HH * WW);
            int gcol = j0 + chunk * 4;
            if (gcol > WW - 4) gcol = WW - 4;    // clamp (garbage lands in unused cells)
            const float* src = base + (size_t)(i0 + rr) * WW + gcol;
            __builtin_amdgcn_global_load_lds(
                (const __attribute__((address_space(1))) void*)src,
                (__attribute__((address_space(3))) void*)(slot + row * LC + chunk * 4),
                16, 0, 0);
        }
    }
}

__global__ __launch_bounds__(256) void flex_conv_v8(
    const float* __restrict__ x, const float* __restrict__ kern,
    const float* __restrict__ pts, float* __restrict__ out)
{
    __shared__ float lds[2 * TILEF];   // 10336 floats = 41344 B -> 3 blocks/CU

    const int tid = threadIdx.x;
    const int j0 = blockIdx.x * TC;
    const int ch = blockIdx.y;            // row-pair chunk: tiles 4ch .. 4ch+3
    const int b = blockIdx.z;

    const float* xb = x + (size_t)b * IC * HH * WW;
    const float* pb = pts + (size_t)b * 3 * HH * WW;

    // tile u top row (clamped: ytile 31 -> i0 60, benign identical rewrite)
    int i0s[NT];
    #pragma unroll
    for (int u = 0; u < NT; ++u) {
        int i0 = 2 * (4 * ch + u);
        if (i0 > HP - RB) i0 = HP - RB;
        i0s[u] = i0;
    }

    // ---- prologue: stage tile 0 into slot 0 ----
    stage_tile(xb, pb, lds, i0s[0], j0, tid);

    // ---- A fragments (overlap the prologue DMA) ----
    const int lane = tid & 63;
    const int wave = tid >> 6;
    const int p = lane & 15;
    const int c = lane >> 4;
    const int tc = wave * 16 + p;        // tile col of this lane's pixel

    short8 a0lo, a0hi, a1lo, a1hi;
    {
        const float4* k0v = (const float4*)(kern + (size_t)p * 64 + c * 8);
        const float4* k1v = (const float4*)(kern + (size_t)(16 + p) * 64 + c * 8);
        float4 v0a = k0v[0], v0b = k0v[1], v0c = k0v[8], v0d = k0v[9];
        float4 v1a = k1v[0], v1b = k1v[1], v1c = k1v[8], v1d = k1v[9];
        a0lo[0]=f2bf(v0a.x); a0lo[1]=f2bf(v0a.y); a0lo[2]=f2bf(v0a.z); a0lo[3]=f2bf(v0a.w);
        a0lo[4]=f2bf(v0b.x); a0lo[5]=f2bf(v0b.y); a0lo[6]=f2bf(v0b.z); a0lo[7]=f2bf(v0b.w);
        a0hi[0]=f2bf(v0c.x); a0hi[1]=f2bf(v0c.y); a0hi[2]=f2bf(v0c.z); a0hi[3]=f2bf(v0c.w);
        a0hi[4]=f2bf(v0d.x); a0hi[5]=f2bf(v0d.y); a0hi[6]=f2bf(v0d.z); a0hi[7]=f2bf(v0d.w);
        a1lo[0]=f2bf(v1a.x); a1lo[1]=f2bf(v1a.y); a1lo[2]=f2bf(v1a.z); a1lo[3]=f2bf(v1a.w);
        a1lo[4]=f2bf(v1b.x); a1lo[5]=f2bf(v1b.y); a1lo[6]=f2bf(v1b.z); a1lo[7]=f2bf(v1b.w);
        a1hi[0]=f2bf(v1c.x); a1hi[1]=f2bf(v1c.y); a1hi[2]=f2bf(v1c.z); a1hi[3]=f2bf(v1c.w);
        a1hi[4]=f2bf(v1d.x); a1hi[5]=f2bf(v1d.y); a1hi[6]=f2bf(v1d.z); a1hi[7]=f2bf(v1d.w);
    }

    __syncthreads();   // drain prologue DMA

    const int j = j0 + tc;
    float* const outb = out + (size_t)b * OC * HP * WP + j;

    #pragma unroll
    for (int u = 0; u < NT; ++u) {
        // ---- issue next tile's DMA into the other slot (hides under compute) ----
        if (u + 1 < NT)
            stage_tile(xb, pb, lds + ((u + 1) & 1) * TILEF, i0s[u + 1], j0, tid);

        const float* slot = lds + (u & 1) * TILEF;
        const int i0 = i0s[u];

        // ---- window partials from LDS (v4 body) ----
        float xs[4][RB], px0[4][RB], px1[4][RB], px2[4][RB];
        #pragma unroll
        for (int t = 0; t < 4; ++t)
            #pragma unroll
            for (int q = 0; q < RB; ++q) { xs[t][q]=0.f; px0[t][q]=0.f; px1[t][q]=0.f; px2[t][q]=0.f; }
        float c0[RB], c1[RB], c2[RB];

        #pragma unroll
        for (int rr = 0; rr < TR; ++rr) {
            const float* lp0 = slot + (IC * TR + rr) * LC + tc;        // pts plane 0
            const float* lp1 = slot + ((IC + 1) * TR + rr) * LC + tc;
            const float* lp2 = slot + ((IC + 2) * TR + rr) * LC + tc;
            const float pa0 = lp0[0], pm0 = lp0[1], pz0 = lp0[2];
            const float pa1 = lp1[0], pm1 = lp1[1], pz1 = lp1[2];
            const float pa2 = lp2[0], pm2 = lp2[1], pz2 = lp2[2];
            if (rr >= 1 && rr <= RB) { c0[rr-1] = pm0; c1[rr-1] = pm1; c2[rr-1] = pm2; }
            #pragma unroll
            for (int t = 0; t < 4; ++t) {
                const int icp = (t >> 1) * 8 + 2 * c + (t & 1);
                const float* lx = slot + (icp * TR + rr) * LC + tc;
                const float x0 = lx[0], x1 = lx[1], x2 = lx[2];
                const float rsx = x0 + x1 + x2;
                float r0 = pa0 * x0; r0 = fmaf(pm0, x1, r0); r0 = fmaf(pz0, x2, r0);
                float r1 = pa1 * x0; r1 = fmaf(pm1, x1, r1); r1 = fmaf(pz1, x2, r1);
                float r2 = pa2 * x0; r2 = fmaf(pm2, x1, r2); r2 = fmaf(pz2, x2, r2);
                #pragma unroll
                for (int q = 0; q < RB; ++q) {
                    if (rr >= q && rr <= q + 2) {
                        xs[t][q] += rsx; px0[t][q] += r0; px1[t][q] += r1; px2[t][q] += r2;
                    }
                }
            }
        }

        // ---- B fragments -> MFMA -> store (v4 body) ----
        #pragma unroll
        for (int q = 0; q < RB; ++q) {
            short8 blo, bhi;
            #pragma unroll
            for (int t = 0; t < 4; ++t) {
                const short t0 = f2bf(fmaf(c0[q], xs[t][q], -px0[t][q]));
                const short t1 = f2bf(fmaf(c1[q], xs[t][q], -px1[t][q]));
                const short t2 = f2bf(fmaf(c2[q], xs[t][q], -px2[t][q]));
                const short t3 = f2bf(xs[t][q]);
                const int s = (t & 1) * 4;
                if (t < 2) { blo[s+0]=t0; blo[s+1]=t1; blo[s+2]=t2; blo[s+3]=t3; }
                else       { bhi[s+0]=t0; bhi[s+1]=t1; bhi[s+2]=t2; bhi[s+3]=t3; }
            }
            f32x4 acc0 = {0.f,0.f,0.f,0.f}, acc1 = {0.f,0.f,0.f,0.f};
            acc0 = __builtin_amdgcn_mfma_f32_16x16x32_bf16(a0lo, blo, acc0, 0, 0, 0);
            acc0 = __builtin_amdgcn_mfma_f32_16x16x32_bf16(a0hi, bhi, acc0, 0, 0, 0);
            acc1 = __builtin_amdgcn_mfma_f32_16x16x32_bf16(a1lo, blo, acc1, 0, 0, 0);
            acc1 = __builtin_amdgcn_mfma_f32_16x16x32_bf16(a1hi, bhi, acc1, 0, 0, 0);
            if (j < WP) {
                float* ob = outb + (size_t)(i0 + q) * WP;
                #pragma unroll
                for (int r = 0; r < 4; ++r) {
                    const int o = c * 4 + r;
                    ob[(size_t)o * HP * WP]        = acc0[r];
                    ob[(size_t)(o + 16) * HP * WP] = acc1[r];
                }
            }
        }

        // barrier AFTER compute: drains the prefetch (hidden under compute
        // above) and protects slot u&1 from being restaged next iteration.
        if (u + 1 < NT) __syncthreads();
    }
}

extern "C" void kernel_launch(void* const* d_in, const int* in_sizes, int n_in,
                              void* d_out, int out_size, void* d_ws, size_t ws_size,
                              hipStream_t stream)
{
    const float* x    = (const float*)d_in[0];
    const float* kern = (const float*)d_in[1];
    const float* pts  = (const float*)d_in[2];
    float* out = (float*)d_out;

    dim3 block(256, 1, 1);
    dim3 grid(WW / TC, 8, BS);   // 8 x 8 x 16 = 1024 blocks, 4 tiles each
    flex_conv_v8<<<grid, block, 0, stream>>>(x, kern, pts, out);
}

// Round 9
// 110.357 us; speedup vs baseline: 1.0615x; 1.0615x over previous
//
#include <hip/hip_runtime.h>
#include <hip/hip_bf16.h>

// flex_conv via MFMA + async LDS staging (v9 = v3 restored — measured best).
//
// Math (unchanged, validated): t[k=ic*4+d][pixel]: t_d = ctr_d*Xs - PX_d
// (d<3), t_3 = Xs; out[o][pixel] = Kmat[o][k] . t[k][pixel] -> 16x16x32 bf16
// MFMA (A[m=p][k], B[k][n=p], D row=c*4+r col=p).
//
// Session scoreboard (kernel-dispatch us): v1 sync-LDS 41.5 | v2 persistent
// pipe 42.5 | v3 async single-barrier ~38 (best) | v4 RB=2 42.1 | v5 no-LDS
// 46.4 | v6 reg-sweep 63 | v7 coalesced-epilogue 47.6 | v8 dbuf pipe 67.
// Falsified: barrier-convoy (v5), occupancy-capacity (v4), LDS-staging-cost
// (v5), VALU volume (v6), store amplification (v7, WRITE=1.07x ideal),
// duty-cycle pipelining (v8).  The simplest async structure wins; every
// added within-block phase lengthens the block critical path and regresses.
// Note: TR=6 gives 2-way LDS read aliasing across c-groups (free, m136);
// TR=4 gave 4-way (1.58x) — one reason v3 beats v4.
//
// Structure: block = 256 thr (4 waves) owns a 64-col x 4-row output tile.
// Stage 19 planes x 6 rows x 68 cols (31 KB) via global_load_lds width=16
// (LDS byte offset of chunk cid == cid*16 -> wave-uniform base + lane*16,
// the DMA's required pattern); A-fragment (kernel weight) loads overlap the
// DMA; ONE __syncthreads drains; compute windows from LDS; 4 MFMA per
// output row; scalar stores (already line-merged by L2, v7 measured).

#define HH 64
#define WW 512
#define HP 62
#define WP 510
#define IC 16
#define OC 32
#define BS 16
#define RB 4            // output rows per block
#define TR (RB + 2)     // staged input rows = 6
#define TC 64           // output cols per block
#define LC 68           // LDS row length in floats (need 66; 68 = 17 float4)
#define NPL 19          // planes staged: 16 x + 3 pts
#define CPR 17          // float4 chunks per row (17*4 = 68)
#define NROWS (NPL * TR)        // 114
#define NCHUNK (NROWS * CPR)    // 1938

typedef __attribute__((ext_vector_type(8))) short short8;
typedef __attribute__((ext_vector_type(4))) float f32x4;

static __device__ __forceinline__ short f2bf(float f) {
    union { __hip_bfloat16 h; short s; } u;
    u.h = __float2bfloat16(f);
    return u.s;
}

__global__ __launch_bounds__(256) void flex_conv_v9(
    const float* __restrict__ x, const float* __restrict__ kern,
    const float* __restrict__ pts, float* __restrict__ out)
{
    __shared__ float lds[NPL * TR * LC];   // 7752 floats = 31008 B

    const int tid = threadIdx.x;
    const int j0 = blockIdx.x * TC;
    int i0 = blockIdx.y * RB;
    if (i0 > HP - RB) i0 = HP - RB;        // tail overlap (benign identical rewrite)
    const int b = blockIdx.z;

    const float* xb = x + (size_t)b * IC * HH * WW;
    const float* pb = pts + (size_t)b * 3 * HH * WW;

    // ---- async cooperative staging: 1938 16B chunks over 256 threads ----
    #pragma unroll
    for (int rnd = 0; rnd < 8; ++rnd) {
        const int cid = tid + rnd * 256;
        if (cid < NCHUNK) {
            const int row = cid / CPR;           // 0..113 = plane*TR + rr
            const int chunk = cid - row * CPR;   // 0..16
            const int plane = row / TR;          // 0..18
            const int rr = row - plane * TR;     // 0..5
            const float* base = (plane < IC)
                ? (xb + (size_t)plane * HH * WW)
                : (pb + (size_t)(plane - IC) * HH * WW);
            int gcol = j0 + chunk * 4;
            if (gcol > WW - 4) gcol = WW - 4;    // clamp (garbage lands in unused cells)
            const float* src = base + (size_t)(i0 + rr) * WW + gcol;
            __builtin_amdgcn_global_load_lds(
                (const __attribute__((address_space(1))) void*)src,
                (__attribute__((address_space(3))) void*)(&lds[row * LC + chunk * 4]),
                16, 0, 0);
        }
    }

    // ---- A fragments: loaded while the DMA above is in flight ----
    const int lane = tid & 63;
    const int wave = tid >> 6;
    const int p = lane & 15;
    const int c = lane >> 4;
    const int tc = wave * 16 + p;        // tile col of this lane's pixel

    short8 a0lo, a0hi, a1lo, a1hi;
    {
        const float4* k0v = (const float4*)(kern + (size_t)p * 64 + c * 8);
        const float4* k1v = (const float4*)(kern + (size_t)(16 + p) * 64 + c * 8);
        float4 v0a = k0v[0], v0b = k0v[1], v0c = k0v[8], v0d = k0v[9];
        float4 v1a = k1v[0], v1b = k1v[1], v1c = k1v[8], v1d = k1v[9];
        a0lo[0]=f2bf(v0a.x); a0lo[1]=f2bf(v0a.y); a0lo[2]=f2bf(v0a.z); a0lo[3]=f2bf(v0a.w);
        a0lo[4]=f2bf(v0b.x); a0lo[5]=f2bf(v0b.y); a0lo[6]=f2bf(v0b.z); a0lo[7]=f2bf(v0b.w);
        a0hi[0]=f2bf(v0c.x); a0hi[1]=f2bf(v0c.y); a0hi[2]=f2bf(v0c.z); a0hi[3]=f2bf(v0c.w);
        a0hi[4]=f2bf(v0d.x); a0hi[5]=f2bf(v0d.y); a0hi[6]=f2bf(v0d.z); a0hi[7]=f2bf(v0d.w);
        a1lo[0]=f2bf(v1a.x); a1lo[1]=f2bf(v1a.y); a1lo[2]=f2bf(v1a.z); a1lo[3]=f2bf(v1a.w);
        a1lo[4]=f2bf(v1b.x); a1lo[5]=f2bf(v1b.y); a1lo[6]=f2bf(v1b.z); a1lo[7]=f2bf(v1b.w);
        a1hi[0]=f2bf(v1c.x); a1hi[1]=f2bf(v1c.y); a1hi[2]=f2bf(v1c.z); a1hi[3]=f2bf(v1c.w);
        a1hi[4]=f2bf(v1d.x); a1hi[5]=f2bf(v1d.y); a1hi[6]=f2bf(v1d.z); a1hi[7]=f2bf(v1d.w);
    }

    __syncthreads();   // drains staging DMA (vmcnt(0)) + barrier

    // ---- window partials from LDS ----
    float xs[4][RB], px0[4][RB], px1[4][RB], px2[4][RB];
    #pragma unroll
    for (int t = 0; t < 4; ++t)
        #pragma unroll
        for (int q = 0; q < RB; ++q) { xs[t][q]=0.f; px0[t][q]=0.f; px1[t][q]=0.f; px2[t][q]=0.f; }
    float c0[RB], c1[RB], c2[RB];

    #pragma unroll
    for (int rr = 0; rr < TR; ++rr) {
        const float* lp0 = &lds[(IC * TR + rr) * LC + tc];        // pts plane 0
        const float* lp1 = &lds[((IC + 1) * TR + rr) * LC + tc];
        const float* lp2 = &lds[((IC + 2) * TR + rr) * LC + tc];
        const float pa0 = lp0[0], pm0 = lp0[1], pz0 = lp0[2];
        const float pa1 = lp1[0], pm1 = lp1[1], pz1 = lp1[2];
        const float pa2 = lp2[0], pm2 = lp2[1], pz2 = lp2[2];
        if (rr >= 1 && rr <= RB) { c0[rr-1] = pm0; c1[rr-1] = pm1; c2[rr-1] = pm2; }
        #pragma unroll
        for (int t = 0; t < 4; ++t) {
            const int ic = (t >> 1) * 8 + 2 * c + (t & 1);
            const float* lx = &lds[(ic * TR + rr) * LC + tc];
            const float x0 = lx[0], x1 = lx[1], x2 = lx[2];
            const float rsx = x0 + x1 + x2;
            float r0 = pa0 * x0; r0 = fmaf(pm0, x1, r0); r0 = fmaf(pz0, x2, r0);
            float r1 = pa1 * x0; r1 = fmaf(pm1, x1, r1); r1 = fmaf(pz1, x2, r1);
            float r2 = pa2 * x0; r2 = fmaf(pm2, x1, r2); r2 = fmaf(pz2, x2, r2);
            #pragma unroll
            for (int q = 0; q < RB; ++q) {
                if (rr >= q && rr <= q + 2) {
                    xs[t][q] += rsx; px0[t][q] += r0; px1[t][q] += r1; px2[t][q] += r2;
                }
            }
        }
    }

    // ---- per output row: B fragments -> MFMA -> store ----
    const int j = j0 + tc;
    #pragma unroll
    for (int q = 0; q < RB; ++q) {
        short8 blo, bhi;
        #pragma unroll
        for (int t = 0; t < 4; ++t) {
            const short t0 = f2bf(fmaf(c0[q], xs[t][q], -px0[t][q]));
            const short t1 = f2bf(fmaf(c1[q], xs[t][q], -px1[t][q]));
            const short t2 = f2bf(fmaf(c2[q], xs[t][q], -px2[t][q]));
            const short t3 = f2bf(xs[t][q]);
            const int s = (t & 1) * 4;
            if (t < 2) { blo[s+0]=t0; blo[s+1]=t1; blo[s+2]=t2; blo[s+3]=t3; }
            else       { bhi[s+0]=t0; bhi[s+1]=t1; bhi[s+2]=t2; bhi[s+3]=t3; }
        }
        f32x4 acc0 = {0.f,0.f,0.f,0.f}, acc1 = {0.f,0.f,0.f,0.f};
        acc0 = __builtin_amdgcn_mfma_f32_16x16x32_bf16(a0lo, blo, acc0, 0, 0, 0);
        acc0 = __builtin_amdgcn_mfma_f32_16x16x32_bf16(a0hi, bhi, acc0, 0, 0, 0);
        acc1 = __builtin_amdgcn_mfma_f32_16x16x32_bf16(a1lo, blo, acc1, 0, 0, 0);
        acc1 = __builtin_amdgcn_mfma_f32_16x16x32_bf16(a1hi, bhi, acc1, 0, 0, 0);
        if (j < WP) {
            float* ob = out + (size_t)b * OC * HP * WP + (size_t)(i0 + q) * WP + j;
            #pragma unroll
            for (int r = 0; r < 4; ++r) {
                const int o = c * 4 + r;
                ob[(size_t)o * HP * WP]        = acc0[r];
                ob[(size_t)(o + 16) * HP * WP] = acc1[r];
            }
        }
    }
}

extern "C" void kernel_launch(void* const* d_in, const int* in_sizes, int n_in,
                              void* d_out, int out_size, void* d_ws, size_t ws_size,
                              hipStream_t stream)
{
    const float* x    = (const float*)d_in[0];
    const float* kern = (const float*)d_in[1];
    const float* pts  = (const float*)d_in[2];
    float* out = (float*)d_out;

    dim3 block(256, 1, 1);
    dim3 grid(WW / TC, (HP + RB - 1) / RB, BS);   // 8 x 16 x 16 = 2048 blocks
    flex_conv_v9<<<grid, block, 0, stream>>>(x, kern, pts, out);
}